// Round 1
// baseline (415.078 us; speedup 1.0000x reference)
//
#include <hip/hip_runtime.h>

// TripletAngularMarginLoss: bs=16384, d=64 (== number of classes)
// out = mean(relu(0.5 + ap - an)) + mean(relu(0.8-ap)) + mean(relu(an-0.4)) + CE
// where ap[i] = min_{t[j]==t[i]} cos(x_i,x_j), an[i] = max_{t[j]!=t[i]} cos(x_i,x_j)

#define N_ROWS 16384
#define N_DIM 64

typedef __attribute__((ext_vector_type(8))) short bf16x8;
typedef __attribute__((ext_vector_type(4))) float f32x4;

__device__ inline unsigned short f2bf(float f) {
  unsigned u = __float_as_uint(f);
  unsigned r = u + 0x7fffu + ((u >> 16) & 1u);   // round-to-nearest-even
  return (unsigned short)(r >> 16);
}

// order-preserving float->uint encoding for atomicMin/atomicMax
__device__ inline unsigned enc_key(float f) {
  unsigned u = __float_as_uint(f);
  return (u & 0x80000000u) ? ~u : (u | 0x80000000u);
}
__device__ inline float dec_key(unsigned k) {
  unsigned u = (k & 0x80000000u) ? (k ^ 0x80000000u) : ~k;
  return __uint_as_float(u);
}

// ---------------- Kernel A: normalize rows, emit bf16 copy, CE term ----------
__global__ void prep_kernel(const float* __restrict__ x, const int* __restrict__ tgt,
                            unsigned short* __restrict__ xb, float* __restrict__ ce_acc) {
  const int row  = blockIdx.x * 4 + (threadIdx.x >> 6);
  const int lane = threadIdx.x & 63;
  float v  = x[row * N_DIM + lane];
  float ss = v * v;
#pragma unroll
  for (int s = 1; s < 64; s <<= 1) ss += __shfl_xor(ss, s, 64);
  float xn = v * rsqrtf(ss);
  xb[row * N_DIM + lane] = f2bf(xn);

  // log-softmax over the 64 normalized features
  float mx = xn;
#pragma unroll
  for (int s = 1; s < 64; s <<= 1) mx = fmaxf(mx, __shfl_xor(mx, s, 64));
  float e  = __expf(xn - mx);
  float se = e;
#pragma unroll
  for (int s = 1; s < 64; s <<= 1) se += __shfl_xor(se, s, 64);
  float lse = mx + __logf(se);
  int   t   = tgt[row];                 // wave-uniform
  float xt  = __shfl(xn, t, 64);
  if (lane == 0) atomicAdd(ce_acc, lse - xt);
}

// ---------------- Kernel B: MFMA similarity tiles + hard mining --------------
// grid = 64 i-blocks * 16 j-splits = 1024 blocks of 256 threads (4 waves).
// Each wave: 64 i-rows, A-fragments register-resident, sweeps 1024 j-cols.
__global__ void mine_kernel(const unsigned short* __restrict__ xb, const int* __restrict__ tgt,
                            unsigned* __restrict__ mp_key, unsigned* __restrict__ mn_key) {
  const int lane    = threadIdx.x & 63;
  const int wv      = threadIdx.x >> 6;
  const int iblk    = blockIdx.x >> 4;
  const int jspl    = blockIdx.x & 15;
  const int rowbase = iblk * 256 + wv * 64;
  const int m = lane & 15, q = lane >> 4;

  // A fragments: lane holds row (rowbase+tr*16+m), k = q*8..q*8+7 (+32 for ks=1)
  bf16x8 a[4][2];
#pragma unroll
  for (int tr = 0; tr < 4; ++tr) {
    const unsigned short* p = xb + (rowbase + tr * 16 + m) * N_DIM + q * 8;
    a[tr][0] = *(const bf16x8*)(p);
    a[tr][1] = *(const bf16x8*)(p + 32);
  }
  // row targets for the C/D rows this lane owns: row = tr*16 + q*4 + r
  int ti[4][4];
#pragma unroll
  for (int tr = 0; tr < 4; ++tr)
#pragma unroll
    for (int r = 0; r < 4; ++r)
      ti[tr][r] = tgt[rowbase + tr * 16 + q * 4 + r];

  float mp[16], mn[16];
#pragma unroll
  for (int k = 0; k < 16; ++k) { mp[k] = __builtin_inff(); mn[k] = -__builtin_inff(); }

  const int jbase = jspl * (N_ROWS / 16);
  for (int jt = 0; jt < 16; ++jt) {
    const int jb = jbase + jt * 64;
#pragma unroll
    for (int tc = 0; tc < 4; ++tc) {
      const int col = jb + tc * 16 + m;           // this lane's output column
      const int tj  = tgt[col];
      const unsigned short* p = xb + col * N_DIM + q * 8;
      bf16x8 b0 = *(const bf16x8*)(p);
      bf16x8 b1 = *(const bf16x8*)(p + 32);
#pragma unroll
      for (int tr = 0; tr < 4; ++tr) {
        f32x4 acc = {0.f, 0.f, 0.f, 0.f};
        acc = __builtin_amdgcn_mfma_f32_16x16x32_bf16(a[tr][0], b0, acc, 0, 0, 0);
        acc = __builtin_amdgcn_mfma_f32_16x16x32_bf16(a[tr][1], b1, acc, 0, 0, 0);
#pragma unroll
        for (int r = 0; r < 4; ++r) {
          const bool  pos = (tj == ti[tr][r]);
          const float d   = acc[r];
          const int   k   = tr * 4 + r;
          mp[k] = fminf(mp[k], pos ? d : __builtin_inff());
          mn[k] = fmaxf(mn[k], pos ? -__builtin_inff() : d);
        }
      }
    }
  }

  // reduce across the 16 lanes (m = 0..15) inside each q-group
#pragma unroll
  for (int s = 1; s < 16; s <<= 1) {
#pragma unroll
    for (int k = 0; k < 16; ++k) {
      mp[k] = fminf(mp[k], __shfl_xor(mp[k], s, 64));
      mn[k] = fmaxf(mn[k], __shfl_xor(mn[k], s, 64));
    }
  }
  if (m == 0) {
#pragma unroll
    for (int tr = 0; tr < 4; ++tr)
#pragma unroll
      for (int r = 0; r < 4; ++r) {
        const int row = rowbase + tr * 16 + q * 4 + r;
        atomicMin(&mp_key[row], enc_key(mp[tr * 4 + r]));
        atomicMax(&mn_key[row], enc_key(mn[tr * 4 + r]));
      }
  }
}

// ---------------- Kernel C: final reduction ---------------------------------
__global__ void finalize_kernel(const unsigned* __restrict__ mp_key, const unsigned* __restrict__ mn_key,
                                const float* __restrict__ ce_acc, float* __restrict__ out) {
  __shared__ float red[3][4];
  float s1 = 0.f, s2 = 0.f, s3 = 0.f;
  for (int r = threadIdx.x; r < N_ROWS; r += 256) {
    float ap = dec_key(mp_key[r]);
    float an = dec_key(mn_key[r]);
    s1 += fmaxf(0.5f + ap - an, 0.f);
    s2 += fmaxf(0.8f - ap, 0.f);
    s3 += fmaxf(an - 0.4f, 0.f);
  }
#pragma unroll
  for (int s = 1; s < 64; s <<= 1) {
    s1 += __shfl_xor(s1, s, 64);
    s2 += __shfl_xor(s2, s, 64);
    s3 += __shfl_xor(s3, s, 64);
  }
  const int wv = threadIdx.x >> 6;
  if ((threadIdx.x & 63) == 0) { red[0][wv] = s1; red[1][wv] = s2; red[2][wv] = s3; }
  __syncthreads();
  if (threadIdx.x == 0) {
    float t1 = red[0][0] + red[0][1] + red[0][2] + red[0][3];
    float t2 = red[1][0] + red[1][1] + red[1][2] + red[1][3];
    float t3 = red[2][0] + red[2][1] + red[2][2] + red[2][3];
    out[0] = (t1 + t2 + t3 + ce_acc[0]) * (1.0f / N_ROWS);
  }
}

extern "C" void kernel_launch(void* const* d_in, const int* in_sizes, int n_in,
                              void* d_out, int out_size, void* d_ws, size_t ws_size,
                              hipStream_t stream) {
  const float* x   = (const float*)d_in[0];
  const int*   tgt = (const int*)d_in[1];
  char* ws = (char*)d_ws;

  unsigned short* xb     = (unsigned short*)ws;                          // 2 MB bf16 normalized
  unsigned*       mp_key = (unsigned*)(ws + (2u << 20));                 // 64 KB
  unsigned*       mn_key = (unsigned*)(ws + (2u << 20) + (64u << 10));   // 64 KB
  float*          ce_acc = (float*)(ws + (2u << 20) + (128u << 10));     // 4 B
  float*          out    = (float*)d_out;

  // init accumulators (ws is re-poisoned to 0xAA before every launch)
  hipMemsetAsync(mp_key, 0xFF, 64u << 10, stream);  // +inf keys for min
  hipMemsetAsync(mn_key, 0x00, 64u << 10, stream);  // -inf keys for max
  hipMemsetAsync(ce_acc, 0x00, 64, stream);

  prep_kernel<<<N_ROWS / 4, 256, 0, stream>>>(x, tgt, xb, ce_acc);
  mine_kernel<<<(N_ROWS / 256) * 16, 256, 0, stream>>>(xb, tgt, mp_key, mn_key);
  finalize_kernel<<<1, 256, 0, stream>>>(mp_key, mn_key, ce_acc, out);
}

// Round 2
// 159.054 us; speedup vs baseline: 2.6097x; 2.6097x over previous
//
#include <hip/hip_runtime.h>

// TripletAngularMarginLoss: bs=16384, d=64 (== number of classes)
// out = mean(relu(0.5 + ap - an)) + mean(relu(0.8-ap)) + mean(relu(an-0.4)) + CE
// where ap[i] = min_{t[j]==t[i]} cos(x_i,x_j), an[i] = max_{t[j]!=t[i]} cos(x_i,x_j)

#define N_ROWS 16384
#define N_DIM 64

typedef __attribute__((ext_vector_type(8))) short bf16x8;
typedef __attribute__((ext_vector_type(4))) float f32x4;

__device__ inline unsigned short f2bf(float f) {
  unsigned u = __float_as_uint(f);
  unsigned r = u + 0x7fffu + ((u >> 16) & 1u);   // round-to-nearest-even
  return (unsigned short)(r >> 16);
}

// order-preserving float->uint encoding for atomicMin/atomicMax
__device__ inline unsigned enc_key(float f) {
  unsigned u = __float_as_uint(f);
  return (u & 0x80000000u) ? ~u : (u | 0x80000000u);
}
__device__ inline float dec_key(unsigned k) {
  unsigned u = (k & 0x80000000u) ? (k ^ 0x80000000u) : ~k;
  return __uint_as_float(u);
}

// ---------------- Kernel A: normalize rows, emit bf16 copy, per-row CE -------
// NO single-address atomics (R1: 16384 same-address atomicAdds serialized ->
// 212us). CE contribution written per-row, summed in finalize.
__global__ void prep_kernel(const float* __restrict__ x, const int* __restrict__ tgt,
                            unsigned short* __restrict__ xb, float* __restrict__ ce_row) {
  const int row  = blockIdx.x * 4 + (threadIdx.x >> 6);
  const int lane = threadIdx.x & 63;
  float v  = x[row * N_DIM + lane];
  float ss = v * v;
#pragma unroll
  for (int s = 1; s < 64; s <<= 1) ss += __shfl_xor(ss, s, 64);
  float xn = v * rsqrtf(ss);
  xb[row * N_DIM + lane] = f2bf(xn);

  // log-softmax over the 64 normalized features
  float mx = xn;
#pragma unroll
  for (int s = 1; s < 64; s <<= 1) mx = fmaxf(mx, __shfl_xor(mx, s, 64));
  float e  = __expf(xn - mx);
  float se = e;
#pragma unroll
  for (int s = 1; s < 64; s <<= 1) se += __shfl_xor(se, s, 64);
  float lse = mx + __logf(se);
  int   t   = tgt[row];                 // wave-uniform
  float xt  = __shfl(xn, t, 64);
  if (lane == 0) ce_row[row] = lse - xt;
}

// ---------------- Kernel B: MFMA similarity tiles + hard mining --------------
// grid = 64 i-blocks * 16 j-splits = 1024 blocks of 256 threads (4 waves).
// Each wave: 64 i-rows, A-fragments register-resident, sweeps 1024 j-cols.
// B-fragments software-pipelined (distance-1 prefetch) from global/L2.
__global__ void mine_kernel(const unsigned short* __restrict__ xb, const int* __restrict__ tgt,
                            unsigned* __restrict__ mp_key, unsigned* __restrict__ mn_key) {
  const int lane    = threadIdx.x & 63;
  const int wv      = threadIdx.x >> 6;
  const int iblk    = blockIdx.x >> 4;
  const int jspl    = blockIdx.x & 15;
  const int rowbase = iblk * 256 + wv * 64;
  const int m = lane & 15, q = lane >> 4;

  // A fragments: lane holds row (rowbase+tr*16+m), k = q*8..q*8+7 (+32 for ks=1)
  bf16x8 a[4][2];
#pragma unroll
  for (int tr = 0; tr < 4; ++tr) {
    const unsigned short* p = xb + (rowbase + tr * 16 + m) * N_DIM + q * 8;
    a[tr][0] = *(const bf16x8*)(p);
    a[tr][1] = *(const bf16x8*)(p + 32);
  }
  // row targets for the C/D rows this lane owns: row = tr*16 + q*4 + r
  int ti[4][4];
#pragma unroll
  for (int tr = 0; tr < 4; ++tr)
#pragma unroll
    for (int r = 0; r < 4; ++r)
      ti[tr][r] = tgt[rowbase + tr * 16 + q * 4 + r];

  float mp[16], mn[16];
#pragma unroll
  for (int k = 0; k < 16; ++k) { mp[k] = __builtin_inff(); mn[k] = -__builtin_inff(); }

  const int jbase = jspl * (N_ROWS / 16);

  // prologue: load column group jc=0
  const unsigned short* p0 = xb + (jbase + m) * N_DIM + q * 8;
  bf16x8 b0 = *(const bf16x8*)p0;
  bf16x8 b1 = *(const bf16x8*)(p0 + 32);
  int    tj = tgt[jbase + m];

  for (int jc = 0; jc < 64; ++jc) {
    bf16x8 cb0 = b0, cb1 = b1;
    int    ctj = tj;
    if (jc < 63) {                       // wave-uniform prefetch of jc+1
      const int ncol = jbase + (jc + 1) * 16 + m;
      const unsigned short* np = xb + ncol * N_DIM + q * 8;
      b0 = *(const bf16x8*)np;
      b1 = *(const bf16x8*)(np + 32);
      tj = tgt[ncol];
    }
#pragma unroll
    for (int tr = 0; tr < 4; ++tr) {
      f32x4 acc = {0.f, 0.f, 0.f, 0.f};
      acc = __builtin_amdgcn_mfma_f32_16x16x32_bf16(a[tr][0], cb0, acc, 0, 0, 0);
      acc = __builtin_amdgcn_mfma_f32_16x16x32_bf16(a[tr][1], cb1, acc, 0, 0, 0);
#pragma unroll
      for (int r = 0; r < 4; ++r) {
        const bool  pos = (ctj == ti[tr][r]);
        const float d   = acc[r];
        const int   k   = tr * 4 + r;
        mp[k] = fminf(mp[k], pos ? d : __builtin_inff());
        mn[k] = fmaxf(mn[k], pos ? -__builtin_inff() : d);
      }
    }
  }

  // reduce across the 16 lanes (m = 0..15) inside each q-group
#pragma unroll
  for (int s = 1; s < 16; s <<= 1) {
#pragma unroll
    for (int k = 0; k < 16; ++k) {
      mp[k] = fminf(mp[k], __shfl_xor(mp[k], s, 64));
      mn[k] = fmaxf(mn[k], __shfl_xor(mn[k], s, 64));
    }
  }
  if (m == 0) {
#pragma unroll
    for (int tr = 0; tr < 4; ++tr)
#pragma unroll
      for (int r = 0; r < 4; ++r) {
        const int row = rowbase + tr * 16 + q * 4 + r;
        atomicMin(&mp_key[row], enc_key(mp[tr * 4 + r]));
        atomicMax(&mn_key[row], enc_key(mn[tr * 4 + r]));
      }
  }
}

// ---------------- Kernel C: final reduction (1024 threads, 16 waves) ---------
__global__ void finalize_kernel(const unsigned* __restrict__ mp_key, const unsigned* __restrict__ mn_key,
                                const float* __restrict__ ce_row, float* __restrict__ out) {
  __shared__ float red[4][16];
  float s1 = 0.f, s2 = 0.f, s3 = 0.f, s4 = 0.f;
  for (int r = threadIdx.x; r < N_ROWS; r += 1024) {
    float ap = dec_key(mp_key[r]);
    float an = dec_key(mn_key[r]);
    s1 += fmaxf(0.5f + ap - an, 0.f);
    s2 += fmaxf(0.8f - ap, 0.f);
    s3 += fmaxf(an - 0.4f, 0.f);
    s4 += ce_row[r];
  }
#pragma unroll
  for (int s = 1; s < 64; s <<= 1) {
    s1 += __shfl_xor(s1, s, 64);
    s2 += __shfl_xor(s2, s, 64);
    s3 += __shfl_xor(s3, s, 64);
    s4 += __shfl_xor(s4, s, 64);
  }
  const int wv = threadIdx.x >> 6;
  if ((threadIdx.x & 63) == 0) {
    red[0][wv] = s1; red[1][wv] = s2; red[2][wv] = s3; red[3][wv] = s4;
  }
  __syncthreads();
  if (threadIdx.x == 0) {
    float t = 0.f;
#pragma unroll
    for (int c = 0; c < 4; ++c) {
      float tc = 0.f;
#pragma unroll
      for (int w = 0; w < 16; ++w) tc += red[c][w];
      t += tc;
    }
    out[0] = t * (1.0f / N_ROWS);
  }
}

extern "C" void kernel_launch(void* const* d_in, const int* in_sizes, int n_in,
                              void* d_out, int out_size, void* d_ws, size_t ws_size,
                              hipStream_t stream) {
  const float* x   = (const float*)d_in[0];
  const int*   tgt = (const int*)d_in[1];
  char* ws = (char*)d_ws;

  unsigned short* xb     = (unsigned short*)ws;                          // 2 MB bf16 normalized
  unsigned*       mp_key = (unsigned*)(ws + (2u << 20));                 // 64 KB
  unsigned*       mn_key = (unsigned*)(ws + (2u << 20) + (64u << 10));   // 64 KB
  float*          ce_row = (float*)(ws + (2u << 20) + (128u << 10));     // 64 KB
  float*          out    = (float*)d_out;

  // init min/max accumulators (ws is re-poisoned to 0xAA before every launch)
  hipMemsetAsync(mp_key, 0xFF, 64u << 10, stream);  // +inf keys for min
  hipMemsetAsync(mn_key, 0x00, 64u << 10, stream);  // -inf keys for max

  prep_kernel<<<N_ROWS / 4, 256, 0, stream>>>(x, tgt, xb, ce_row);
  mine_kernel<<<(N_ROWS / 256) * 16, 256, 0, stream>>>(xb, tgt, mp_key, mn_key);
  finalize_kernel<<<1, 1024, 0, stream>>>(mp_key, mn_key, ce_row, out);
}